// Round 17
// baseline (1116.033 us; speedup 1.0000x reference)
//
#include <hip/hip_runtime.h>

// KalmanNet recurrent step, MFMA fp16, r17: phase E split (mirror of r16's fix).
//
// r16 post-mortem: per-gate phase-C split delivered (1125->1035us, WRITE
// 146->124MB, absmax bit-identical => order invariant held). Remaining
// arch-budget violator: phase E = A hi/lo (32) + TWO B streams x depth-1
// (32) + ptrs ~= 72 > 64. r17 splits phase E into two sequential
// single-B-stream passes (E1: all waves, tile wid; E2: waves 0-3, tile
// 16+wid), both between the same barriers, per-column accumulation order
// unchanged => bitwise-identical absmax. Everything else = r16.
//
// Base: BR=32, 1024thr (16 waves, full chip), a1/a2 single-fp16
// (r11-validated), h hi/lo, W1/W3 in LDS, z-acc parked in LDS (r16),
// parity-LDS state, bias folding (W1 ones-row k=8 -> b1; h-pad
// k_h=200==1.0 + g_w2 row 200 -> b2).
//
// Fragment maps (verified r2-r16): A/B k = kt*32 + (lane>>4)*8 + i,
// A row / B col = lane&15; C/D col = lane&15, row = (lane>>4)*4 + reg.

namespace {

constexpr int T_STEPS = 32;
constexpr int BATCH   = 8192;
constexpr int H1      = 480;
constexpr int HID     = 200;
constexpr int H2      = 320;
constexpr int BR      = 32;    // batch rows per block (2 MFMA m-tiles)
constexpr int NTHR    = 1024;  // 16 waves, 4/SIMD, 1 block/CU
constexpr int KTG     = 22;    // gates K tiles (704 = 480 a1 + 224 h/pad)
constexpr int KTA     = 15;    // a1 K tiles (480)
constexpr int NTG     = 52;    // 4 groups x 13 real j-tiles
constexpr int NTW1    = 30;    // W1 real col tiles (480/16)
constexpr int NT2     = 20;    // W2 real col tiles (320/16)
constexpr int KT2     = 7;     // W2 / h K tiles (224)
constexpr int KT3     = 10;    // W3 K tiles (320)

using f16x8 = __attribute__((ext_vector_type(8))) _Float16;
using f32x4 = __attribute__((ext_vector_type(4))) float;

__device__ _Float16 g_w1[NTW1 * 512];          // [nt][lane][8], k=8 row = b1
__device__ _Float16 g_wcat[NTG * KTG * 512];   // [grp*13+tile][kt][lane][8]
__device__ _Float16 g_w2[NT2 * KT2 * 512];     // [nt][kt][lane][8], k_h=200 = b2
__device__ _Float16 g_w3[KT3 * 512];           // [kt][lane][8], cols 8..15 = 0

#define MFMA16(A, B, C) __builtin_amdgcn_mfma_f32_16x16x32_f16((A), (B), (C), 0, 0, 0)
#define SBAR() __builtin_amdgcn_sched_barrier(0)

__device__ __forceinline__ float sigmoid_(float x) { return 1.f / (1.f + __expf(-x)); }
__device__ __forceinline__ float tanh_(float x) {
  x = fminf(fmaxf(x, -15.f), 15.f);
  const float e = __expf(-2.f * x);
  return (1.f - e) / (1.f + e);
}
__device__ __forceinline__ f16x8 f16x8_zero() {
  f16x8 v;
#pragma unroll
  for (int i = 0; i < 8; ++i) v[i] = (_Float16)0.f;
  return v;
}

// (k, r) -> flat half index; layout [kt][m=r>>4][lane=((k&31)>>3)*16+(r&15)][i=k&7]
__device__ __forceinline__ int fragoff(int k, int r) {
  const int kt = k >> 5, kk = k & 31;
  return kt * 1024 + ((r >> 4) * 512) + ((((kk >> 3) << 4) | (r & 15)) * 8) + (kk & 7);
}

// ---------------- weight pre-pack (identical to r16) ----------------
__global__ __launch_bounds__(256) void prep_kernel(
    const float* __restrict__ W1, const float* __restrict__ b1,
    const float* __restrict__ Wg, const float* __restrict__ Ug,
    const float* __restrict__ W2, const float* __restrict__ b2,
    const float* __restrict__ W3) {
  const int idx = blockIdx.x * 256 + threadIdx.x;
  constexpr int TOTW1 = NTW1 * 512;
  constexpr int TOT1  = NTG * KTG * 512;
  constexpr int TOT2  = NT2 * KT2 * 512;
  constexpr int TOT3  = KT3 * 512;
  if (idx < TOTW1) {
    const int i = idx & 7, l = (idx >> 3) & 63, nt = idx >> 9;
    const int g = l >> 4, c = l & 15;
    const int k = g * 8 + i, col = nt * 16 + c;   // col < 480 always
    float wv = 0.f;
    if (k < 8) wv = W1[k * H1 + col];
    else if (k == 8) wv = b1[col];
    g_w1[idx] = (_Float16)wv;
  } else if (idx < TOTW1 + TOT1) {
    const int id = idx - TOTW1;
    const int i = id & 7, l = (id >> 3) & 63, nk = id >> 9;
    const int kt = nk % KTG, nt = nk / KTG;
    const int g = l >> 4, c = l & 15;
    const int k = kt * 32 + g * 8 + i;        // 0..703
    const int grp = nt / 13;                  // 0=z 1=r 2=xh 3=hh
    const int jj = (nt - grp * 13) * 16 + c;  // 0..207
    float wv = 0.f;
    if (jj < HID) {
      if (grp == 0) {
        if (k < H1) wv = Wg[k * 600 + jj];
        else if (k < H1 + HID) wv = Ug[(k - H1) * 600 + jj];
      } else if (grp == 1) {
        if (k < H1) wv = Wg[k * 600 + 200 + jj];
        else if (k < H1 + HID) wv = Ug[(k - H1) * 600 + 200 + jj];
      } else if (grp == 2) {
        if (k < H1) wv = Wg[k * 600 + 400 + jj];           // xh: a1 rows only
      } else {
        if (k >= H1 && k < H1 + HID) wv = Ug[(k - H1) * 600 + 400 + jj];  // hh
      }
    }
    g_wcat[id] = (_Float16)wv;
  } else if (idx < TOTW1 + TOT1 + TOT2) {
    const int id = idx - TOTW1 - TOT1;
    const int i = id & 7, l = (id >> 3) & 63, nk = id >> 9;
    const int kt = nk % KT2, nt = nk / KT2;
    const int g = l >> 4, c = l & 15;
    const int k = kt * 32 + g * 8 + i;        // 0..223
    const int col = nt * 16 + c;              // 0..319 (all real)
    float wv = 0.f;
    if (k < HID) wv = W2[k * H2 + col];
    else if (k == 200) wv = b2[col];          // ones-row at k_h=200 (k=680)
    g_w2[id] = (_Float16)wv;
  } else if (idx < TOTW1 + TOT1 + TOT2 + TOT3) {
    const int id = idx - TOTW1 - TOT1 - TOT2;
    const int i = id & 7, l = (id >> 3) & 63, kt = id >> 9;
    const int g = l >> 4, c = l & 15;
    const int k = kt * 32 + g * 8 + i;        // 0..319
    g_w3[id] = (_Float16)((c < 8) ? W3[k * 8 + c] : 0.f);
  }
}

// ---------------- main recurrent kernel ----------------
__global__
__attribute__((amdgpu_flat_work_group_size(NTHR, NTHR)))
__attribute__((amdgpu_waves_per_eu(4, 4)))
void knet_kernel(
    const float* __restrict__ y,    // [T,B,2]
    const float* __restrict__ Fm,   // [4,4]
    const float* __restrict__ Hm,   // [2,4]
    const float* __restrict__ bg,   // [2,600]
    const float* __restrict__ b3,   // [8]
    const float* __restrict__ hn0,  // [B,200]
    float* __restrict__ out)        // [T,B,4]
{
  // a1 (k 0..479) single fp16; slots 0..9 reused for a2 (cols 0..319) E->F
  __shared__ alignas(16) _Float16 sA1[KTA * 2 * 512];    // 30720 B
  // h region (k_h 0..223 incl. 1.0@200 pad), exact hi/lo
  __shared__ alignas(16) _Float16 sAhh[KT2 * 2 * 512];   // 14336 B
  __shared__ alignas(16) _Float16 sAhl[KT2 * 2 * 512];   // 14336 B
  // LDS-resident small weights (r15)
  __shared__ alignas(16) _Float16 sW1[NTW1 * 512];       // 30720 B
  __shared__ alignas(16) _Float16 sW3[KT3 * 512];        // 10240 B
  // parked z-gate accumulator (r16; pad 9 -> conflict-free)
  __shared__ alignas(16) float s_gz[13][64][9];          // 29952 B
  __shared__ alignas(16) float s_in8T[8][BR];
  __shared__ alignas(16) float s_kgp[2][BR][8];          // KG k-half partials
  __shared__ alignas(16) float s_bias[4][HID];
  __shared__ alignas(16) float s_fh[32];                 // Fm[16], Hm[8]
  __shared__ alignas(16) float s_b3[8];
  // persistent per-row filter state, double-buffered by t-parity (r8)
  __shared__ alignas(16) float s_prior2[2][BR][4];
  __shared__ alignas(16) float s_d2[2][BR][2];

  const int tid  = threadIdx.x;
  const int lane = tid & 63;
  const int wid  = __builtin_amdgcn_readfirstlane(tid >> 6);  // 0..15
  const int row0 = blockIdx.x * BR;
  const int rl   = lane & 31;
  const int g4   = (lane >> 4) << 2;
  const int ab   = lane * 8;
  const int c16  = lane & 15;

  // ---- init ----
  if (tid < HID) {
    s_bias[0][tid] = bg[tid]       + bg[600 + tid];   // z
    s_bias[1][tid] = bg[200 + tid] + bg[800 + tid];   // r
    s_bias[2][tid] = bg[400 + tid];                   // xh (input bias)
    s_bias[3][tid] = bg[1000 + tid];                  // hh (recurrent bias)
  }
  if (tid < 16) s_fh[tid] = Fm[tid];
  else if (tid < 24) s_fh[tid] = Hm[tid - 16];
  if (tid < 8) s_b3[tid] = b3[tid];
  if (tid < BR * 4) s_prior2[0][tid >> 2][tid & 3] = 0.f;
  if (tid < BR * 2) s_d2[0][tid >> 1][tid & 1] = 0.f;
  for (int e = tid * 8; e < NTW1 * 512; e += NTHR * 8)    // g_w1 -> LDS
    *(f16x8*)&sW1[e] = *(const f16x8*)&g_w1[e];
  for (int e = tid * 8; e < KT3 * 512; e += NTHR * 8)     // g_w3 -> LDS
    *(f16x8*)&sW3[e] = *(const f16x8*)&g_w3[e];
  for (int e = tid; e < HID * BR; e += NTHR) {            // hn0 -> hi/lo
    const int j = e >> 5, r = e & 31;
    const float h0 = hn0[(size_t)(row0 + r) * HID + j];
    const int off = fragoff(j, r);
    const _Float16 hi = (_Float16)h0;
    sAhh[off] = hi;
    sAhl[off] = (_Float16)(h0 - (float)hi);
  }
  for (int e = tid; e < 24 * BR; e += NTHR) {   // k_h 200..223: 1.0 then 0
    const int kh = 200 + (e >> 5), r = e & 31;
    const int off = fragoff(kh, r);
    sAhh[off] = (_Float16)((kh == 200) ? 1.f : 0.f);
    sAhl[off] = (_Float16)0.f;
  }
  __syncthreads();

  for (int t = 0; t < T_STEPS; ++t) {
    const int p = t & 1;
    // ================= phase 1: F2(t-1) + A(t) + W1-GEMM(t) =================
    {
      float post[4] = {0.f, 0.f, 0.f, 0.f};
      if (t > 0) {
        float kg[8];
#pragma unroll
        for (int cc = 0; cc < 8; ++cc)
          kg[cc] = s_kgp[0][rl][cc] + s_kgp[1][rl][cc] + s_b3[cc];
        const float pd0 = s_d2[p][rl][0], pd1 = s_d2[p][rl][1];
#pragma unroll
        for (int m = 0; m < 4; ++m)
          post[m] = s_prior2[p][rl][m] + kg[2 * m] * pd0 + kg[2 * m + 1] * pd1;
        if (wid == 0 && lane < BR) {
          float4 o; o.x = post[0]; o.y = post[1]; o.z = post[2]; o.w = post[3];
          *(float4*)&out[((size_t)(t - 1) * BATCH + row0 + rl) * 4] = o;
        }
      }
      // ---- A: prior / innovation / features (redundant per wave) ----
      float opri[4], np[4];
#pragma unroll
      for (int m = 0; m < 4; ++m) opri[m] = s_prior2[p][rl][m];
#pragma unroll
      for (int m = 0; m < 4; ++m) {
        float s = 0.f;
#pragma unroll
        for (int j = 0; j < 4; ++j) s += s_fh[m * 4 + j] * post[j];
        np[m] = s;
      }
      float m0 = 0.f, m1 = 0.f;
#pragma unroll
      for (int m = 0; m < 4; ++m) { m0 += s_fh[16 + m] * np[m]; m1 += s_fh[20 + m] * np[m]; }
      const float2 yv = *(const float2*)&y[((size_t)t * BATCH + row0 + rl) * 2];
      const float d0 = yv.x - m0;
      const float d1 = yv.y - m1;
      float dx[4], ssx = 0.f;
#pragma unroll
      for (int m = 0; m < 4; ++m) { dx[m] = post[m] - opri[m]; ssx += dx[m] * dx[m]; }
      const float idx_ = rsqrtf(fmaxf(ssx, 1e-12f));
      const float idy_ = rsqrtf(fmaxf(d0 * d0 + d1 * d1, 1e-12f));
      if (lane < BR) {   // identical values from all waves: benign
#pragma unroll
        for (int m = 0; m < 4; ++m) s_prior2[p ^ 1][rl][m] = np[m];
        s_d2[p ^ 1][rl][0] = d0;
        s_d2[p ^ 1][rl][1] = d1;
        const float n0 = d0 * idy_, n1 = d1 * idy_;
        s_in8T[0][rl] = n0; s_in8T[1][rl] = n1;
        s_in8T[2][rl] = n0; s_in8T[3][rl] = n1;
#pragma unroll
        for (int m = 0; m < 4; ++m) s_in8T[4 + m][rl] = dx[m] * idx_;
      }
    }
    {   // ---- W1-GEMM: a1 = relu([in8,1] @ [W1;b1]), 2 tiles/wave, B in LDS ----
      f16x8 ah0 = f16x8_zero(), al0 = f16x8_zero();
      f16x8 ah1 = f16x8_zero(), al1 = f16x8_zero();
      const int g = lane >> 4;
      if (g == 0) {
#pragma unroll
        for (int i = 0; i < 8; ++i) {
          const float v0 = s_in8T[i][c16];
          const float v1 = s_in8T[i][c16 + 16];
          const _Float16 h0 = (_Float16)v0; ah0[i] = h0; al0[i] = (_Float16)(v0 - (float)h0);
          const _Float16 h1 = (_Float16)v1; ah1[i] = h1; al1[i] = (_Float16)(v1 - (float)h1);
        }
      } else if (g == 1) {
        ah0[0] = (_Float16)1.f;   // ones-row k=8 -> b1
        ah1[0] = (_Float16)1.f;
      }
      f32x4 p00 = {0.f, 0.f, 0.f, 0.f}, p01 = p00, p10 = p00, p11 = p00;
      const f16x8 w1a = *(const f16x8*)&sW1[(size_t)wid * 512 + ab];
      p00 = MFMA16(ah0, w1a, p00); p00 = MFMA16(al0, w1a, p00);
      p01 = MFMA16(ah1, w1a, p01); p01 = MFMA16(al1, w1a, p01);
      const bool hasB = (wid < 14);
      if (hasB) {
        const f16x8 w1b = *(const f16x8*)&sW1[(size_t)(16 + wid) * 512 + ab];
        p10 = MFMA16(ah0, w1b, p10); p10 = MFMA16(al0, w1b, p10);
        p11 = MFMA16(ah1, w1b, p11); p11 = MFMA16(al1, w1b, p11);
      }
      // single-fp16 a1 store (r11-validated numerics)
#define ASTORE1(A0, A1, COLBASE)                                     \
      { const int col = (COLBASE) + c16;                             \
        _Pragma("unroll")                                            \
        for (int reg = 0; reg < 4; ++reg) {                          \
          sA1[fragoff(col, g4 + reg)]      = (_Float16)fmaxf(A0[reg], 0.f); \
          sA1[fragoff(col, 16 + g4 + reg)] = (_Float16)fmaxf(A1[reg], 0.f); \
        } }
      ASTORE1(p00, p01, wid * 16)
      if (hasB) ASTORE1(p10, p11, (16 + wid) * 16)
    }
    __syncthreads();

    // ======= phase C: gates GEMM, three per-gate passes (waves 0..12) =======
    // Per-gate kt order identical to r15 => bitwise-identical accumulation.
    f32x4 aR0 = {0.f, 0.f, 0.f, 0.f}, aR1 = aR0;
    f32x4 aX0 = aR0, aX1 = aR0, aH0 = aR0, aH1 = aR0;
    if (wid < 13) {
      const _Float16* bzp = g_wcat + ((size_t)(0  + wid) * KTG) * 512 + ab;
      const _Float16* brp = g_wcat + ((size_t)(13 + wid) * KTG) * 512 + ab;
      const _Float16* bxp = g_wcat + ((size_t)(26 + wid) * KTG) * 512 + ab;
      const _Float16* bhp = g_wcat + ((size_t)(39 + wid) * KTG) * 512 + ab;

      // ---- pass Z: single B stream, acc -> parked in LDS ----
      {
        f32x4 aZ0 = {0.f, 0.f, 0.f, 0.f}, aZ1 = aZ0;
        f16x8 bC = *(const f16x8*)(bzp);
#pragma unroll
        for (int kt = 0; kt < KTG; ++kt) {
          f16x8 bN;
          if (kt + 1 < KTG) bN = *(const f16x8*)(bzp + (kt + 1) * 512);
          if (kt < KTA) {
            const int _o = kt * 1024 + ab;
            const f16x8 ca0 = *(const f16x8*)&sA1[_o];
            const f16x8 ca1 = *(const f16x8*)&sA1[_o + 512];
            SBAR();
            aZ0 = MFMA16(ca0, bC, aZ0);
            aZ1 = MFMA16(ca1, bC, aZ1);
          } else {
            const int _o = (kt - KTA) * 1024 + ab;
            const f16x8 cah0 = *(const f16x8*)&sAhh[_o];
            const f16x8 cal0 = *(const f16x8*)&sAhl[_o];
            const f16x8 cah1 = *(const f16x8*)&sAhh[_o + 512];
            const f16x8 cal1 = *(const f16x8*)&sAhl[_o + 512];
            SBAR();
            aZ0 = MFMA16(cah0, bC, aZ0);  aZ0 = MFMA16(cal0, bC, aZ0);
            aZ1 = MFMA16(cah1, bC, aZ1);  aZ1 = MFMA16(cal1, bC, aZ1);
          }
          if (kt + 1 < KTG) bC = bN;
        }
#pragma unroll
        for (int q = 0; q < 4; ++q) {          // park (thread-private slot)
          s_gz[wid][lane][q]     = aZ0[q];
          s_gz[wid][lane][4 + q] = aZ1[q];
        }
      }

      // ---- pass R: single B stream, acc stays in regs ----
      {
        f16x8 bC = *(const f16x8*)(brp);
#pragma unroll
        for (int kt = 0; kt < KTG; ++kt) {
          f16x8 bN;
          if (kt + 1 < KTG) bN = *(const f16x8*)(brp + (kt + 1) * 512);
          if (kt < KTA) {
            const int _o = kt * 1024 + ab;
            const f16x8 ca0 = *(const f16x8*)&sA1[_o];
            const f16x8 ca1 = *(const f16x8*)&sA1[_o + 512];
            SBAR();
            aR0 = MFMA16(ca0, bC, aR0);
            aR1 = MFMA16(ca1, bC, aR1);
          } else {
            const int _o = (kt - KTA) * 1024 + ab;
            const f16x8 cah0 = *(const f16x8*)&sAhh[_o];
            const f16x8 cal0 = *(const f16x8*)&sAhl[_o];
            const f16x8 cah1 = *(const f16x8*)&sAhh[_o + 512];
            const f16x8 cal1 = *(const f16x8*)&sAhl[_o + 512];
            SBAR();
            aR0 = MFMA16(cah0, bC, aR0);  aR0 = MFMA16(cal0, bC, aR0);
            aR1 = MFMA16(cah1, bC, aR1);  aR1 = MFMA16(cal1, bC, aR1);
          }
          if (kt + 1 < KTG) bC = bN;
        }
      }

      // ---- pass XH: x (kt<15, single A) then hh (kt>=15, hi/lo A) ----
      {
        f16x8 bC = *(const f16x8*)(bxp);
#pragma unroll
        for (int kt = 0; kt < KTG; ++kt) {
          f16x8 bN;
          if (kt + 1 < KTG)
            bN = (kt + 1 < KTA) ? *(const f16x8*)(bxp + (kt + 1) * 512)
                                : *(const f16x8*)(bhp + (kt + 1) * 512);
          if (kt < KTA) {
            const int _o = kt * 1024 + ab;
            const f16x8 ca0 = *(const f16x8*)&sA1[_o];
            const f16x8 ca1 = *(const f16x8*)&sA1[_o + 512];
            SBAR();
            aX0 = MFMA16(ca0, bC, aX0);
            aX1 = MFMA16(ca1, bC, aX1);
          } else {
            const int _o = (kt - KTA) * 1024 + ab;
            const f16x8 cah0 = *(const f16x8*)&sAhh[_o];
            const f16x8 cal0 = *(const f16x8*)&sAhl[_o];
            const f16x8 cah1 = *(const f16x8*)&sAhh[_o + 512];
            const f16x8 cal1 = *(const f16x8*)&sAhl[_o + 512];
            SBAR();
            aH0 = MFMA16(cah0, bC, aH0);  aH0 = MFMA16(cal0, bC, aH0);
            aH1 = MFMA16(cah1, bC, aH1);  aH1 = MFMA16(cal1, bC, aH1);
          }
          if (kt + 1 < KTG) bC = bN;
        }
      }
    }
    __syncthreads();   // all h reads done before in-place h update

    // ================= phase D: in-register GRU update =================
    if (wid < 13) {
      const int j = wid * 16 + c16;
      if (j < HID) {
        const float bz  = s_bias[0][j], brb = s_bias[1][j];
        const float bxh = s_bias[2][j], bhh = s_bias[3][j];
#define GRU1(AR, AX, AH, MB)                                             \
        _Pragma("unroll")                                                \
        for (int reg = 0; reg < 4; ++reg) {                              \
          const int r = (MB) * 16 + g4 + reg;                            \
          const int off = fragoff(j, r);                                 \
          const float hold = (float)sAhh[off] + (float)sAhl[off];        \
          const float z  = sigmoid_(s_gz[wid][lane][(MB) * 4 + reg] + bz); \
          const float rr = sigmoid_(AR[reg] + brb);                      \
          const float hc = tanh_((AX[reg] + bxh) + rr * (AH[reg] + bhh));\
          const float hn = z * hold + (1.f - z) * hc;                    \
          const _Float16 qh = (_Float16)hn;                              \
          sAhh[off] = qh;                                                \
          sAhl[off] = (_Float16)(hn - (float)qh);                       \
        }
        GRU1(aR0, aX0, aH0, 0)
        GRU1(aR1, aX1, aH1, 1)
#undef GRU1
      }
    }
    __syncthreads();

    // ==== phase E: a2 = relu(h @ W2 + b2); two single-B-stream passes ====
    {
      // ---- pass E1: all waves, tile wid ----
      {
        f32x4 e00 = {0.f, 0.f, 0.f, 0.f}, e01 = e00;
        const _Float16* w2a = g_w2 + ((size_t)wid * KT2) * 512 + ab;
        f16x8 bC = *(const f16x8*)(w2a);
#pragma unroll
        for (int qt = 0; qt < KT2; ++qt) {
          f16x8 bN;
          if (qt + 1 < KT2) bN = *(const f16x8*)(w2a + (qt + 1) * 512);
          const int _o = qt * 1024 + ab;
          const f16x8 cah0 = *(const f16x8*)&sAhh[_o];
          const f16x8 cal0 = *(const f16x8*)&sAhl[_o];
          const f16x8 cah1 = *(const f16x8*)&sAhh[_o + 512];
          const f16x8 cal1 = *(const f16x8*)&sAhl[_o + 512];
          SBAR();
          e00 = MFMA16(cah0, bC, e00); e00 = MFMA16(cal0, bC, e00);
          e01 = MFMA16(cah1, bC, e01); e01 = MFMA16(cal1, bC, e01);
          if (qt + 1 < KT2) bC = bN;
        }
        ASTORE1(e00, e01, wid * 16)                     // cols < 256
      }
      // ---- pass E2: waves 0..3, tile 16+wid ----
      if (wid < 4) {
        f32x4 e10 = {0.f, 0.f, 0.f, 0.f}, e11 = e10;
        const _Float16* w2b = g_w2 + ((size_t)(16 + wid) * KT2) * 512 + ab;
        f16x8 bC = *(const f16x8*)(w2b);
#pragma unroll
        for (int qt = 0; qt < KT2; ++qt) {
          f16x8 bN;
          if (qt + 1 < KT2) bN = *(const f16x8*)(w2b + (qt + 1) * 512);
          const int _o = qt * 1024 + ab;
          const f16x8 cah0 = *(const f16x8*)&sAhh[_o];
          const f16x8 cal0 = *(const f16x8*)&sAhl[_o];
          const f16x8 cah1 = *(const f16x8*)&sAhh[_o + 512];
          const f16x8 cal1 = *(const f16x8*)&sAhl[_o + 512];
          SBAR();
          e10 = MFMA16(cah0, bC, e10); e10 = MFMA16(cal0, bC, e10);
          e11 = MFMA16(cah1, bC, e11); e11 = MFMA16(cal1, bC, e11);
          if (qt + 1 < KT2) bC = bN;
        }
        ASTORE1(e10, e11, (16 + wid) * 16)              // cols 256..319
      }
#undef ASTORE1
    }
    __syncthreads();

    // ===== phase F: KG partials (waves 0..3 = m-half x k-half; W3 in LDS) =====
    if (wid < 4) {
      const int mB = wid & 1, half = wid >> 1;
      f32x4 ka = {0.f, 0.f, 0.f, 0.f};
#pragma unroll
      for (int q = 0; q < 5; ++q) {
        const int kt3 = half * 5 + q;
        const int _o = kt3 * 1024 + mB * 512 + ab;
        const f16x8 a  = *(const f16x8*)&sA1[_o];
        const f16x8 bw = *(const f16x8*)&sW3[kt3 * 512 + ab];
        ka = MFMA16(a, bw, ka);
      }
      if (c16 < 8) {
        const int rb = mB * 16 + g4;
#pragma unroll
        for (int reg = 0; reg < 4; ++reg) s_kgp[half][rb + reg][c16] = ka[reg];
      }
    }
    __syncthreads();
  }

  // ---- final F2 (t = T_STEPS, parity 0) ----
  {
    float kg[8];
#pragma unroll
    for (int cc = 0; cc < 8; ++cc)
      kg[cc] = s_kgp[0][rl][cc] + s_kgp[1][rl][cc] + s_b3[cc];
    const float pd0 = s_d2[0][rl][0], pd1 = s_d2[0][rl][1];
    if (wid == 0 && lane < BR) {
      float4 o;
      o.x = s_prior2[0][rl][0] + kg[0] * pd0 + kg[1] * pd1;
      o.y = s_prior2[0][rl][1] + kg[2] * pd0 + kg[3] * pd1;
      o.z = s_prior2[0][rl][2] + kg[4] * pd0 + kg[5] * pd1;
      o.w = s_prior2[0][rl][3] + kg[6] * pd0 + kg[7] * pd1;
      *(float4*)&out[((size_t)(T_STEPS - 1) * BATCH + row0 + rl) * 4] = o;
    }
  }
}

}  // namespace

extern "C" void kernel_launch(void* const* d_in, const int* in_sizes, int n_in,
                              void* d_out, int out_size, void* d_ws, size_t ws_size,
                              hipStream_t stream) {
  const float* y   = (const float*)d_in[0];
  const float* Fm  = (const float*)d_in[1];
  const float* Hm  = (const float*)d_in[2];
  const float* W1  = (const float*)d_in[3];
  const float* b1  = (const float*)d_in[4];
  const float* Wg  = (const float*)d_in[5];
  const float* Ug  = (const float*)d_in[6];
  const float* bg  = (const float*)d_in[7];
  const float* W2  = (const float*)d_in[8];
  const float* b2  = (const float*)d_in[9];
  const float* W3  = (const float*)d_in[10];
  const float* b3  = (const float*)d_in[11];
  const float* hn0 = (const float*)d_in[12];
  float* out = (float*)d_out;

  constexpr int PREP_TOT = (NTW1 + NTG * KTG + NT2 * KT2 + KT3) * 512;
  prep_kernel<<<(PREP_TOT + 255) / 256, 256, 0, stream>>>(W1, b1, Wg, Ug, W2, b2, W3);
  knet_kernel<<<BATCH / BR, NTHR, 0, stream>>>(y, Fm, Hm, bg, b3, hn0, out);
}

// Round 18
// 1063.039 us; speedup vs baseline: 1.0499x; 1.0499x over previous
//
#include <hip/hip_runtime.h>

// KalmanNet recurrent step, MFMA fp16, r18: revert to r16 (verified best).
//
// r17 post-mortem: phase-E split regressed (1035->1116us): the E2 tail (4 of
// 16 waves for 7 serialized iters) cost more than the register relief saved,
// and WRITE barely moved (124->117MB) => phase E was not the spill source.
// Split-pass lesson: pays when wave-parallelism is preserved (phase C, r16),
// loses when it creates a narrow tail (r17) or extends acc lifetimes across
// barriers (r14).
//
// r16 structure (this kernel): BR=32, 1024thr (16 waves, 4/SIMD, full chip);
// a1/a2 single-fp16 (r11-validated: absmax bit-identical), h hi/lo fp16;
// W1/W3 LDS-resident (r15); phase C = three per-gate single-B-stream passes
// with z-acc parked in LDS (r16); parity-LDS filter state (r8); bias folding
// (W1 ones-row k=8 -> b1; h-pad k_h=200==1.0 + g_w2 row 200 -> b2).
// Session ladder: 4115 -> 3014 -> 2288 -> 2056 -> 1675 -> 1500 -> 1390 ->
// 1349 -> 1178 -> 1125 -> 1035 (this kernel).
//
// Fragment maps (verified r2-r17): A/B k = kt*32 + (lane>>4)*8 + i,
// A row / B col = lane&15; C/D col = lane&15, row = (lane>>4)*4 + reg.

namespace {

constexpr int T_STEPS = 32;
constexpr int BATCH   = 8192;
constexpr int H1      = 480;
constexpr int HID     = 200;
constexpr int H2      = 320;
constexpr int BR      = 32;    // batch rows per block (2 MFMA m-tiles)
constexpr int NTHR    = 1024;  // 16 waves, 4/SIMD, 1 block/CU
constexpr int KTG     = 22;    // gates K tiles (704 = 480 a1 + 224 h/pad)
constexpr int KTA     = 15;    // a1 K tiles (480)
constexpr int NTG     = 52;    // 4 groups x 13 real j-tiles
constexpr int NTW1    = 30;    // W1 real col tiles (480/16)
constexpr int NT2     = 20;    // W2 real col tiles (320/16)
constexpr int KT2     = 7;     // W2 / h K tiles (224)
constexpr int KT3     = 10;    // W3 K tiles (320)

using f16x8 = __attribute__((ext_vector_type(8))) _Float16;
using f32x4 = __attribute__((ext_vector_type(4))) float;

__device__ _Float16 g_w1[NTW1 * 512];          // [nt][lane][8], k=8 row = b1
__device__ _Float16 g_wcat[NTG * KTG * 512];   // [grp*13+tile][kt][lane][8]
__device__ _Float16 g_w2[NT2 * KT2 * 512];     // [nt][kt][lane][8], k_h=200 = b2
__device__ _Float16 g_w3[KT3 * 512];           // [kt][lane][8], cols 8..15 = 0

#define MFMA16(A, B, C) __builtin_amdgcn_mfma_f32_16x16x32_f16((A), (B), (C), 0, 0, 0)
#define SBAR() __builtin_amdgcn_sched_barrier(0)

__device__ __forceinline__ float sigmoid_(float x) { return 1.f / (1.f + __expf(-x)); }
__device__ __forceinline__ float tanh_(float x) {
  x = fminf(fmaxf(x, -15.f), 15.f);
  const float e = __expf(-2.f * x);
  return (1.f - e) / (1.f + e);
}
__device__ __forceinline__ f16x8 f16x8_zero() {
  f16x8 v;
#pragma unroll
  for (int i = 0; i < 8; ++i) v[i] = (_Float16)0.f;
  return v;
}

// (k, r) -> flat half index; layout [kt][m=r>>4][lane=((k&31)>>3)*16+(r&15)][i=k&7]
__device__ __forceinline__ int fragoff(int k, int r) {
  const int kt = k >> 5, kk = k & 31;
  return kt * 1024 + ((r >> 4) * 512) + ((((kk >> 3) << 4) | (r & 15)) * 8) + (kk & 7);
}

// ---------------- weight pre-pack (identical to r16) ----------------
__global__ __launch_bounds__(256) void prep_kernel(
    const float* __restrict__ W1, const float* __restrict__ b1,
    const float* __restrict__ Wg, const float* __restrict__ Ug,
    const float* __restrict__ W2, const float* __restrict__ b2,
    const float* __restrict__ W3) {
  const int idx = blockIdx.x * 256 + threadIdx.x;
  constexpr int TOTW1 = NTW1 * 512;
  constexpr int TOT1  = NTG * KTG * 512;
  constexpr int TOT2  = NT2 * KT2 * 512;
  constexpr int TOT3  = KT3 * 512;
  if (idx < TOTW1) {
    const int i = idx & 7, l = (idx >> 3) & 63, nt = idx >> 9;
    const int g = l >> 4, c = l & 15;
    const int k = g * 8 + i, col = nt * 16 + c;   // col < 480 always
    float wv = 0.f;
    if (k < 8) wv = W1[k * H1 + col];
    else if (k == 8) wv = b1[col];
    g_w1[idx] = (_Float16)wv;
  } else if (idx < TOTW1 + TOT1) {
    const int id = idx - TOTW1;
    const int i = id & 7, l = (id >> 3) & 63, nk = id >> 9;
    const int kt = nk % KTG, nt = nk / KTG;
    const int g = l >> 4, c = l & 15;
    const int k = kt * 32 + g * 8 + i;        // 0..703
    const int grp = nt / 13;                  // 0=z 1=r 2=xh 3=hh
    const int jj = (nt - grp * 13) * 16 + c;  // 0..207
    float wv = 0.f;
    if (jj < HID) {
      if (grp == 0) {
        if (k < H1) wv = Wg[k * 600 + jj];
        else if (k < H1 + HID) wv = Ug[(k - H1) * 600 + jj];
      } else if (grp == 1) {
        if (k < H1) wv = Wg[k * 600 + 200 + jj];
        else if (k < H1 + HID) wv = Ug[(k - H1) * 600 + 200 + jj];
      } else if (grp == 2) {
        if (k < H1) wv = Wg[k * 600 + 400 + jj];           // xh: a1 rows only
      } else {
        if (k >= H1 && k < H1 + HID) wv = Ug[(k - H1) * 600 + 400 + jj];  // hh
      }
    }
    g_wcat[id] = (_Float16)wv;
  } else if (idx < TOTW1 + TOT1 + TOT2) {
    const int id = idx - TOTW1 - TOT1;
    const int i = id & 7, l = (id >> 3) & 63, nk = id >> 9;
    const int kt = nk % KT2, nt = nk / KT2;
    const int g = l >> 4, c = l & 15;
    const int k = kt * 32 + g * 8 + i;        // 0..223
    const int col = nt * 16 + c;              // 0..319 (all real)
    float wv = 0.f;
    if (k < HID) wv = W2[k * H2 + col];
    else if (k == 200) wv = b2[col];          // ones-row at k_h=200 (k=680)
    g_w2[id] = (_Float16)wv;
  } else if (idx < TOTW1 + TOT1 + TOT2 + TOT3) {
    const int id = idx - TOTW1 - TOT1 - TOT2;
    const int i = id & 7, l = (id >> 3) & 63, kt = id >> 9;
    const int g = l >> 4, c = l & 15;
    const int k = kt * 32 + g * 8 + i;        // 0..319
    g_w3[id] = (_Float16)((c < 8) ? W3[k * 8 + c] : 0.f);
  }
}

// ---------------- main recurrent kernel ----------------
__global__
__attribute__((amdgpu_flat_work_group_size(NTHR, NTHR)))
__attribute__((amdgpu_waves_per_eu(4, 4)))
void knet_kernel(
    const float* __restrict__ y,    // [T,B,2]
    const float* __restrict__ Fm,   // [4,4]
    const float* __restrict__ Hm,   // [2,4]
    const float* __restrict__ bg,   // [2,600]
    const float* __restrict__ b3,   // [8]
    const float* __restrict__ hn0,  // [B,200]
    float* __restrict__ out)        // [T,B,4]
{
  // a1 (k 0..479) single fp16; slots 0..9 reused for a2 (cols 0..319) E->F
  __shared__ alignas(16) _Float16 sA1[KTA * 2 * 512];    // 30720 B
  // h region (k_h 0..223 incl. 1.0@200 pad), exact hi/lo
  __shared__ alignas(16) _Float16 sAhh[KT2 * 2 * 512];   // 14336 B
  __shared__ alignas(16) _Float16 sAhl[KT2 * 2 * 512];   // 14336 B
  // LDS-resident small weights (r15)
  __shared__ alignas(16) _Float16 sW1[NTW1 * 512];       // 30720 B
  __shared__ alignas(16) _Float16 sW3[KT3 * 512];        // 10240 B
  // parked z-gate accumulator (r16; pad 9 -> conflict-free)
  __shared__ alignas(16) float s_gz[13][64][9];          // 29952 B
  __shared__ alignas(16) float s_in8T[8][BR];
  __shared__ alignas(16) float s_kgp[2][BR][8];          // KG k-half partials
  __shared__ alignas(16) float s_bias[4][HID];
  __shared__ alignas(16) float s_fh[32];                 // Fm[16], Hm[8]
  __shared__ alignas(16) float s_b3[8];
  // persistent per-row filter state, double-buffered by t-parity (r8)
  __shared__ alignas(16) float s_prior2[2][BR][4];
  __shared__ alignas(16) float s_d2[2][BR][2];

  const int tid  = threadIdx.x;
  const int lane = tid & 63;
  const int wid  = __builtin_amdgcn_readfirstlane(tid >> 6);  // 0..15
  const int row0 = blockIdx.x * BR;
  const int rl   = lane & 31;
  const int g4   = (lane >> 4) << 2;
  const int ab   = lane * 8;
  const int c16  = lane & 15;

  // ---- init ----
  if (tid < HID) {
    s_bias[0][tid] = bg[tid]       + bg[600 + tid];   // z
    s_bias[1][tid] = bg[200 + tid] + bg[800 + tid];   // r
    s_bias[2][tid] = bg[400 + tid];                   // xh (input bias)
    s_bias[3][tid] = bg[1000 + tid];                  // hh (recurrent bias)
  }
  if (tid < 16) s_fh[tid] = Fm[tid];
  else if (tid < 24) s_fh[tid] = Hm[tid - 16];
  if (tid < 8) s_b3[tid] = b3[tid];
  if (tid < BR * 4) s_prior2[0][tid >> 2][tid & 3] = 0.f;
  if (tid < BR * 2) s_d2[0][tid >> 1][tid & 1] = 0.f;
  for (int e = tid * 8; e < NTW1 * 512; e += NTHR * 8)    // g_w1 -> LDS
    *(f16x8*)&sW1[e] = *(const f16x8*)&g_w1[e];
  for (int e = tid * 8; e < KT3 * 512; e += NTHR * 8)     // g_w3 -> LDS
    *(f16x8*)&sW3[e] = *(const f16x8*)&g_w3[e];
  for (int e = tid; e < HID * BR; e += NTHR) {            // hn0 -> hi/lo
    const int j = e >> 5, r = e & 31;
    const float h0 = hn0[(size_t)(row0 + r) * HID + j];
    const int off = fragoff(j, r);
    const _Float16 hi = (_Float16)h0;
    sAhh[off] = hi;
    sAhl[off] = (_Float16)(h0 - (float)hi);
  }
  for (int e = tid; e < 24 * BR; e += NTHR) {   // k_h 200..223: 1.0 then 0
    const int kh = 200 + (e >> 5), r = e & 31;
    const int off = fragoff(kh, r);
    sAhh[off] = (_Float16)((kh == 200) ? 1.f : 0.f);
    sAhl[off] = (_Float16)0.f;
  }
  __syncthreads();

  for (int t = 0; t < T_STEPS; ++t) {
    const int p = t & 1;
    // ================= phase 1: F2(t-1) + A(t) + W1-GEMM(t) =================
    {
      float post[4] = {0.f, 0.f, 0.f, 0.f};
      if (t > 0) {
        float kg[8];
#pragma unroll
        for (int cc = 0; cc < 8; ++cc)
          kg[cc] = s_kgp[0][rl][cc] + s_kgp[1][rl][cc] + s_b3[cc];
        const float pd0 = s_d2[p][rl][0], pd1 = s_d2[p][rl][1];
#pragma unroll
        for (int m = 0; m < 4; ++m)
          post[m] = s_prior2[p][rl][m] + kg[2 * m] * pd0 + kg[2 * m + 1] * pd1;
        if (wid == 0 && lane < BR) {
          float4 o; o.x = post[0]; o.y = post[1]; o.z = post[2]; o.w = post[3];
          *(float4*)&out[((size_t)(t - 1) * BATCH + row0 + rl) * 4] = o;
        }
      }
      // ---- A: prior / innovation / features (redundant per wave) ----
      float opri[4], np[4];
#pragma unroll
      for (int m = 0; m < 4; ++m) opri[m] = s_prior2[p][rl][m];
#pragma unroll
      for (int m = 0; m < 4; ++m) {
        float s = 0.f;
#pragma unroll
        for (int j = 0; j < 4; ++j) s += s_fh[m * 4 + j] * post[j];
        np[m] = s;
      }
      float m0 = 0.f, m1 = 0.f;
#pragma unroll
      for (int m = 0; m < 4; ++m) { m0 += s_fh[16 + m] * np[m]; m1 += s_fh[20 + m] * np[m]; }
      const float2 yv = *(const float2*)&y[((size_t)t * BATCH + row0 + rl) * 2];
      const float d0 = yv.x - m0;
      const float d1 = yv.y - m1;
      float dx[4], ssx = 0.f;
#pragma unroll
      for (int m = 0; m < 4; ++m) { dx[m] = post[m] - opri[m]; ssx += dx[m] * dx[m]; }
      const float idx_ = rsqrtf(fmaxf(ssx, 1e-12f));
      const float idy_ = rsqrtf(fmaxf(d0 * d0 + d1 * d1, 1e-12f));
      if (lane < BR) {   // identical values from all waves: benign
#pragma unroll
        for (int m = 0; m < 4; ++m) s_prior2[p ^ 1][rl][m] = np[m];
        s_d2[p ^ 1][rl][0] = d0;
        s_d2[p ^ 1][rl][1] = d1;
        const float n0 = d0 * idy_, n1 = d1 * idy_;
        s_in8T[0][rl] = n0; s_in8T[1][rl] = n1;
        s_in8T[2][rl] = n0; s_in8T[3][rl] = n1;
#pragma unroll
        for (int m = 0; m < 4; ++m) s_in8T[4 + m][rl] = dx[m] * idx_;
      }
    }
    {   // ---- W1-GEMM: a1 = relu([in8,1] @ [W1;b1]), 2 tiles/wave, B in LDS ----
      f16x8 ah0 = f16x8_zero(), al0 = f16x8_zero();
      f16x8 ah1 = f16x8_zero(), al1 = f16x8_zero();
      const int g = lane >> 4;
      if (g == 0) {
#pragma unroll
        for (int i = 0; i < 8; ++i) {
          const float v0 = s_in8T[i][c16];
          const float v1 = s_in8T[i][c16 + 16];
          const _Float16 h0 = (_Float16)v0; ah0[i] = h0; al0[i] = (_Float16)(v0 - (float)h0);
          const _Float16 h1 = (_Float16)v1; ah1[i] = h1; al1[i] = (_Float16)(v1 - (float)h1);
        }
      } else if (g == 1) {
        ah0[0] = (_Float16)1.f;   // ones-row k=8 -> b1
        ah1[0] = (_Float16)1.f;
      }
      f32x4 p00 = {0.f, 0.f, 0.f, 0.f}, p01 = p00, p10 = p00, p11 = p00;
      const f16x8 w1a = *(const f16x8*)&sW1[(size_t)wid * 512 + ab];
      p00 = MFMA16(ah0, w1a, p00); p00 = MFMA16(al0, w1a, p00);
      p01 = MFMA16(ah1, w1a, p01); p01 = MFMA16(al1, w1a, p01);
      const bool hasB = (wid < 14);
      if (hasB) {
        const f16x8 w1b = *(const f16x8*)&sW1[(size_t)(16 + wid) * 512 + ab];
        p10 = MFMA16(ah0, w1b, p10); p10 = MFMA16(al0, w1b, p10);
        p11 = MFMA16(ah1, w1b, p11); p11 = MFMA16(al1, w1b, p11);
      }
      // single-fp16 a1 store (r11-validated numerics)
#define ASTORE1(A0, A1, COLBASE)                                     \
      { const int col = (COLBASE) + c16;                             \
        _Pragma("unroll")                                            \
        for (int reg = 0; reg < 4; ++reg) {                          \
          sA1[fragoff(col, g4 + reg)]      = (_Float16)fmaxf(A0[reg], 0.f); \
          sA1[fragoff(col, 16 + g4 + reg)] = (_Float16)fmaxf(A1[reg], 0.f); \
        } }
      ASTORE1(p00, p01, wid * 16)
      if (hasB) ASTORE1(p10, p11, (16 + wid) * 16)
    }
    __syncthreads();

    // ======= phase C: gates GEMM, three per-gate passes (waves 0..12) =======
    // Per-gate kt order identical to r15 => bitwise-identical accumulation.
    f32x4 aR0 = {0.f, 0.f, 0.f, 0.f}, aR1 = aR0;
    f32x4 aX0 = aR0, aX1 = aR0, aH0 = aR0, aH1 = aR0;
    if (wid < 13) {
      const _Float16* bzp = g_wcat + ((size_t)(0  + wid) * KTG) * 512 + ab;
      const _Float16* brp = g_wcat + ((size_t)(13 + wid) * KTG) * 512 + ab;
      const _Float16* bxp = g_wcat + ((size_t)(26 + wid) * KTG) * 512 + ab;
      const _Float16* bhp = g_wcat + ((size_t)(39 + wid) * KTG) * 512 + ab;

      // ---- pass Z: single B stream, acc -> parked in LDS ----
      {
        f32x4 aZ0 = {0.f, 0.f, 0.f, 0.f}, aZ1 = aZ0;
        f16x8 bC = *(const f16x8*)(bzp);
#pragma unroll
        for (int kt = 0; kt < KTG; ++kt) {
          f16x8 bN;
          if (kt + 1 < KTG) bN = *(const f16x8*)(bzp + (kt + 1) * 512);
          if (kt < KTA) {
            const int _o = kt * 1024 + ab;
            const f16x8 ca0 = *(const f16x8*)&sA1[_o];
            const f16x8 ca1 = *(const f16x8*)&sA1[_o + 512];
            SBAR();
            aZ0 = MFMA16(ca0, bC, aZ0);
            aZ1 = MFMA16(ca1, bC, aZ1);
          } else {
            const int _o = (kt - KTA) * 1024 + ab;
            const f16x8 cah0 = *(const f16x8*)&sAhh[_o];
            const f16x8 cal0 = *(const f16x8*)&sAhl[_o];
            const f16x8 cah1 = *(const f16x8*)&sAhh[_o + 512];
            const f16x8 cal1 = *(const f16x8*)&sAhl[_o + 512];
            SBAR();
            aZ0 = MFMA16(cah0, bC, aZ0);  aZ0 = MFMA16(cal0, bC, aZ0);
            aZ1 = MFMA16(cah1, bC, aZ1);  aZ1 = MFMA16(cal1, bC, aZ1);
          }
          if (kt + 1 < KTG) bC = bN;
        }
#pragma unroll
        for (int q = 0; q < 4; ++q) {          // park (thread-private slot)
          s_gz[wid][lane][q]     = aZ0[q];
          s_gz[wid][lane][4 + q] = aZ1[q];
        }
      }

      // ---- pass R: single B stream, acc stays in regs ----
      {
        f16x8 bC = *(const f16x8*)(brp);
#pragma unroll
        for (int kt = 0; kt < KTG; ++kt) {
          f16x8 bN;
          if (kt + 1 < KTG) bN = *(const f16x8*)(brp + (kt + 1) * 512);
          if (kt < KTA) {
            const int _o = kt * 1024 + ab;
            const f16x8 ca0 = *(const f16x8*)&sA1[_o];
            const f16x8 ca1 = *(const f16x8*)&sA1[_o + 512];
            SBAR();
            aR0 = MFMA16(ca0, bC, aR0);
            aR1 = MFMA16(ca1, bC, aR1);
          } else {
            const int _o = (kt - KTA) * 1024 + ab;
            const f16x8 cah0 = *(const f16x8*)&sAhh[_o];
            const f16x8 cal0 = *(const f16x8*)&sAhl[_o];
            const f16x8 cah1 = *(const f16x8*)&sAhh[_o + 512];
            const f16x8 cal1 = *(const f16x8*)&sAhl[_o + 512];
            SBAR();
            aR0 = MFMA16(cah0, bC, aR0);  aR0 = MFMA16(cal0, bC, aR0);
            aR1 = MFMA16(cah1, bC, aR1);  aR1 = MFMA16(cal1, bC, aR1);
          }
          if (kt + 1 < KTG) bC = bN;
        }
      }

      // ---- pass XH: x (kt<15, single A) then hh (kt>=15, hi/lo A) ----
      {
        f16x8 bC = *(const f16x8*)(bxp);
#pragma unroll
        for (int kt = 0; kt < KTG; ++kt) {
          f16x8 bN;
          if (kt + 1 < KTG)
            bN = (kt + 1 < KTA) ? *(const f16x8*)(bxp + (kt + 1) * 512)
                                : *(const f16x8*)(bhp + (kt + 1) * 512);
          if (kt < KTA) {
            const int _o = kt * 1024 + ab;
            const f16x8 ca0 = *(const f16x8*)&sA1[_o];
            const f16x8 ca1 = *(const f16x8*)&sA1[_o + 512];
            SBAR();
            aX0 = MFMA16(ca0, bC, aX0);
            aX1 = MFMA16(ca1, bC, aX1);
          } else {
            const int _o = (kt - KTA) * 1024 + ab;
            const f16x8 cah0 = *(const f16x8*)&sAhh[_o];
            const f16x8 cal0 = *(const f16x8*)&sAhl[_o];
            const f16x8 cah1 = *(const f16x8*)&sAhh[_o + 512];
            const f16x8 cal1 = *(const f16x8*)&sAhl[_o + 512];
            SBAR();
            aH0 = MFMA16(cah0, bC, aH0);  aH0 = MFMA16(cal0, bC, aH0);
            aH1 = MFMA16(cah1, bC, aH1);  aH1 = MFMA16(cal1, bC, aH1);
          }
          if (kt + 1 < KTG) bC = bN;
        }
      }
    }
    __syncthreads();   // all h reads done before in-place h update

    // ================= phase D: in-register GRU update =================
    if (wid < 13) {
      const int j = wid * 16 + c16;
      if (j < HID) {
        const float bz  = s_bias[0][j], brb = s_bias[1][j];
        const float bxh = s_bias[2][j], bhh = s_bias[3][j];
#define GRU1(AR, AX, AH, MB)                                             \
        _Pragma("unroll")                                                \
        for (int reg = 0; reg < 4; ++reg) {                              \
          const int r = (MB) * 16 + g4 + reg;                            \
          const int off = fragoff(j, r);                                 \
          const float hold = (float)sAhh[off] + (float)sAhl[off];        \
          const float z  = sigmoid_(s_gz[wid][lane][(MB) * 4 + reg] + bz); \
          const float rr = sigmoid_(AR[reg] + brb);                      \
          const float hc = tanh_((AX[reg] + bxh) + rr * (AH[reg] + bhh));\
          const float hn = z * hold + (1.f - z) * hc;                    \
          const _Float16 qh = (_Float16)hn;                              \
          sAhh[off] = qh;                                                \
          sAhl[off] = (_Float16)(hn - (float)qh);                       \
        }
        GRU1(aR0, aX0, aH0, 0)
        GRU1(aR1, aX1, aH1, 1)
#undef GRU1
      }
    }
    __syncthreads();

    // == phase E: a2 = relu(h @ W2 + b2); h hi/lo A, B depth-1, pinned ==
    {
      f32x4 e00 = {0.f, 0.f, 0.f, 0.f}, e01 = e00, e10 = e00, e11 = e00;
      const _Float16* w2a = g_w2 + ((size_t)wid * KT2) * 512 + ab;
      const _Float16* w2b = g_w2 + ((size_t)(16 + wid) * KT2) * 512 + ab;
      f16x8 baC = *(const f16x8*)(w2a);
      f16x8 bbC = (wid < 4) ? *(const f16x8*)(w2b) : f16x8_zero();
#pragma unroll
      for (int qt = 0; qt < KT2; ++qt) {
        const int _o = qt * 1024 + ab;
        const f16x8 cah0 = *(const f16x8*)&sAhh[_o];
        const f16x8 cal0 = *(const f16x8*)&sAhl[_o];
        const f16x8 cah1 = *(const f16x8*)&sAhh[_o + 512];
        const f16x8 cal1 = *(const f16x8*)&sAhl[_o + 512];
        f16x8 baN, bbN;
        if (qt + 1 < KT2) {
          baN = *(const f16x8*)(w2a + (qt + 1) * 512);
          if (wid < 4) bbN = *(const f16x8*)(w2b + (qt + 1) * 512);
        }
        SBAR();
        e00 = MFMA16(cah0, baC, e00); e00 = MFMA16(cal0, baC, e00);
        e01 = MFMA16(cah1, baC, e01); e01 = MFMA16(cal1, baC, e01);
        if (wid < 4) {
          e10 = MFMA16(cah0, bbC, e10); e10 = MFMA16(cal0, bbC, e10);
          e11 = MFMA16(cah1, bbC, e11); e11 = MFMA16(cal1, bbC, e11);
        }
        if (qt + 1 < KT2) { baC = baN; if (wid < 4) bbC = bbN; }
      }
      // a2 -> sA1 slots 0..9, single fp16 (b2 folded via ones-row)
      ASTORE1(e00, e01, wid * 16)                       // cols < 256
      if (wid < 4) ASTORE1(e10, e11, (16 + wid) * 16)   // cols 256..319
#undef ASTORE1
    }
    __syncthreads();

    // ===== phase F: KG partials (waves 0..3 = m-half x k-half; W3 in LDS) =====
    if (wid < 4) {
      const int mB = wid & 1, half = wid >> 1;
      f32x4 ka = {0.f, 0.f, 0.f, 0.f};
#pragma unroll
      for (int q = 0; q < 5; ++q) {
        const int kt3 = half * 5 + q;
        const int _o = kt3 * 1024 + mB * 512 + ab;
        const f16x8 a  = *(const f16x8*)&sA1[_o];
        const f16x8 bw = *(const f16x8*)&sW3[kt3 * 512 + ab];
        ka = MFMA16(a, bw, ka);
      }
      if (c16 < 8) {
        const int rb = mB * 16 + g4;
#pragma unroll
        for (int reg = 0; reg < 4; ++reg) s_kgp[half][rb + reg][c16] = ka[reg];
      }
    }
    __syncthreads();
  }

  // ---- final F2 (t = T_STEPS, parity 0) ----
  {
    float kg[8];
#pragma unroll
    for (int cc = 0; cc < 8; ++cc)
      kg[cc] = s_kgp[0][rl][cc] + s_kgp[1][rl][cc] + s_b3[cc];
    const float pd0 = s_d2[0][rl][0], pd1 = s_d2[0][rl][1];
    if (wid == 0 && lane < BR) {
      float4 o;
      o.x = s_prior2[0][rl][0] + kg[0] * pd0 + kg[1] * pd1;
      o.y = s_prior2[0][rl][1] + kg[2] * pd0 + kg[3] * pd1;
      o.z = s_prior2[0][rl][2] + kg[4] * pd0 + kg[5] * pd1;
      o.w = s_prior2[0][rl][3] + kg[6] * pd0 + kg[7] * pd1;
      *(float4*)&out[((size_t)(T_STEPS - 1) * BATCH + row0 + rl) * 4] = o;
    }
  }
}

}  // namespace

extern "C" void kernel_launch(void* const* d_in, const int* in_sizes, int n_in,
                              void* d_out, int out_size, void* d_ws, size_t ws_size,
                              hipStream_t stream) {
  const float* y   = (const float*)d_in[0];
  const float* Fm  = (const float*)d_in[1];
  const float* Hm  = (const float*)d_in[2];
  const float* W1  = (const float*)d_in[3];
  const float* b1  = (const float*)d_in[4];
  const float* Wg  = (const float*)d_in[5];
  const float* Ug  = (const float*)d_in[6];
  const float* bg  = (const float*)d_in[7];
  const float* W2  = (const float*)d_in[8];
  const float* b2  = (const float*)d_in[9];
  const float* W3  = (const float*)d_in[10];
  const float* b3  = (const float*)d_in[11];
  const float* hn0 = (const float*)d_in[12];
  float* out = (float*)d_out;

  constexpr int PREP_TOT = (NTW1 + NTG * KTG + NT2 * KT2 + KT3) * 512;
  prep_kernel<<<(PREP_TOT + 255) / 256, 256, 0, stream>>>(W1, b1, Wg, Ug, W2, b2, W3);
  knet_kernel<<<BATCH / BR, NTHR, 0, stream>>>(y, Fm, Hm, bg, b3, hn0, out);
}